// Round 4
// baseline (254.414 us; speedup 1.0000x reference)
//
#include <hip/hip_runtime.h>

// MultiscaleLLN: out = x / (gauss13x13(lum(x)) / dens + eps), 4 pyramid levels.
// Separable Gaussian; dens analytic via prefix sums.
// R4: XCD-aware block swizzle (kept — FETCH 194->115 MB).
// R5/R6: vectorized LDS convs + phase-4 VGPR prefetch + padded strides (kept;
//        measured NEUTRAL -> LDS issue was not the limiter).
// R7: dense-VMEM theory. All global x accesses were float4 at 48 B/lane
//     stride: each wave VMEM instruction touched 48 cachelines per 1 KB
//     payload (3x the dense 16). TA/TD line-transaction amplification is the
//     pipe invariant across R0/R1/R6 (dur pinned at ~90 us while traffic and
//     LDS mix changed). Rework phases 1 & 4 to one PIXEL (12 B float3) per
//     lane: consecutive lanes cover contiguous 768 B per instruction
//     (dwordx3, line-dense). Phases 2/3, LDS layout, occupancy unchanged.

#define NPIX   87040
#define EPSV   1e-3f
#define WSUM   0.9999f      // 0.2989 + 0.587 + 0.114
#define TW     64
#define TH     16
#define RAD    6
#define LW     80           // lum px per row: [tx0-8, tx0+72)
#define LWP    84           // padded stride for s_lum
#define RCP    68           // padded stride for s_rc/s_scale
#define LH     28           // lum rows: [ty0-6, ty0+22)
#define NPXH   (LH * LW)    // 2240 halo pixels per tile
#define NBLK   11008
#define NXCD   8
#define CHUNK  (NBLK / NXCD)   // 1376, exact

// 1D Gaussian taps G1[d+6] = exp(-d^2/18)/sqrt(18*pi), d = -6..6
__device__ __constant__ float G1[13] = {
    0.01799699f, 0.03315904f, 0.05467002f, 0.08065689f, 0.10648267f,
    0.12579441f, 0.13298076f, 0.12579441f, 0.10648267f, 0.08065689f,
    0.05467002f, 0.03315904f, 0.01799699f
};
// prefix sums PRE[i] = sum_{j<i} G1[j]
__device__ __constant__ float PRE[14] = {
    0.00000000f, 0.01799699f, 0.05115603f, 0.10582605f, 0.18648294f,
    0.29296561f, 0.41876002f, 0.55174078f, 0.67753519f, 0.78401786f,
    0.86467475f, 0.91934477f, 0.95250381f, 0.97050080f
};

struct F3 { float x, y, z; };   // 12 B, align 4 -> global_load/store_dwordx3

__global__ __launch_bounds__(256)
void mslln_kernel(const float* __restrict__ x, float* __restrict__ out) {
    // s_scale aliases s_lum: s_lum dead after phase 2, barrier before phase 3.
    __shared__ float s_mem[LH * LWP];          // 28*84*4 = 9408 B
    __shared__ float s_rc[LH][RCP];            // 28*68*4 = 7616 B  (tot 17024)
    float (*s_lum)[LWP]   = (float(*)[LWP])s_mem;
    float (*s_scale)[RCP] = (float(*)[RCP])s_mem;

    // XCD-aware swizzle: physical block b lands on XCD b%8 (round-robin
    // dispatch); give XCD k the contiguous logical range [k*1376,(k+1)*1376).
    const int bphys = blockIdx.x;
    const int bid   = (bphys & (NXCD - 1)) * CHUNK + (bphys >> 3);
    const int t     = threadIdx.x;

    // block -> (level, image, tile); tiles are 64x16 outputs
    int img, tl, txlog, h, off;
    if (bid < 8192)       { img = bid >> 6;                 tl = bid & 63; txlog = 2; h = 256; off = 0;     }
    else if (bid < 10240) { int r = bid - 8192;  img = r >> 4; tl = r & 15; txlog = 1; h = 128; off = 65536; }
    else if (bid < 10752) { int r = bid - 10240; img = r >> 2; tl = r & 3;  txlog = 0; h = 64;  off = 81920; }
    else                  { int r = bid - 10752; img = r >> 1; tl = r & 1;  txlog = 0; h = 32;  off = 86016; }
    const int w   = h;
    const int tx0 = (tl & ((1 << txlog) - 1)) << 6;  // *64
    const int ty0 = (tl >> txlog) << 4;              // *16

    const float* __restrict__ xb = x   + (size_t)img * (NPIX * 3) + (size_t)off * 3;
    float*       __restrict__ ob = out + (size_t)img * (NPIX * 3) + (size_t)off * 3;

    // ---- Phase 1: per-pixel float3 load (line-dense), lum -> LDS ----
    // 2240 px = 8.75 * 256; consecutive lanes -> consecutive pixels (12 B
    // apart) -> each wave load instruction covers one contiguous 768 B run.
#pragma unroll
    for (int k = 0; k < 9; k++) {
        int i = t + (k << 8);
        if (i < NPXH) {
            int r  = i / LW;           // compiler magic-mul
            int c  = i - r * LW;
            int gy = ty0 + r - RAD;
            int gx = tx0 + c - 8;
            float lum = 0.f;
            if (gy >= 0 && gy < h && gx >= 0 && gx < w) {
                F3 v = *(const F3*)(xb + ((size_t)gy * w + gx) * 3);
                lum = 0.2989f * v.x + 0.587f * v.y + 0.114f * v.z;
            }
            s_lum[r][c] = lum;         // stride-1 b32 writes, conflict-free
        }
    }
    __syncthreads();

    // ---- Phase 2a: prefetch phase-4 RGB into VGPRs (per-pixel, dense;
    //      L1/L2-hot from phase 1; latency hides under the row conv) ----
    F3 pf[4];
#pragma unroll
    for (int j = 0; j < 4; j++) {
        int P   = t + (j << 8);        // 1024 output px per tile
        int row = P >> 6, col = P & 63;
        int gx  = tx0 + col;
        pf[j].x = 0.f; pf[j].y = 0.f; pf[j].z = 0.f;
        if (gx < w)                    // only false on L3 (w=32)
            pf[j] = *(const F3*)(xb + ((size_t)(ty0 + row) * w + gx) * 3);
    }

    // ---- Phase 2b: row conv, 28 rows x 16 groups of 4 = 448 groups ----
    // s_lum[r][c] holds pixel gx = tx0 + c - 8; output col c taps cols c+2..c+14.
    // Sliding window: group c4 needs cols [c4+2, c4+18) -> load [c4, c4+20).
#pragma unroll
    for (int k = 0; k < 2; k++) {
        int gi = t + (k << 8);
        if (gi < 448) {
            int r  = gi >> 4;
            int c4 = (gi & 15) << 2;
            float a[20];
#pragma unroll
            for (int m = 0; m < 5; m++)
                *(float4*)&a[m << 2] = *(const float4*)&s_lum[r][c4 + (m << 2)];
            float s0 = 0.f, s1 = 0.f, s2 = 0.f, s3 = 0.f;
#pragma unroll
            for (int j = 0; j < 13; j++) {
                float gj = G1[j];
                s0 += a[2 + j] * gj;
                s1 += a[3 + j] * gj;
                s2 += a[4 + j] * gj;
                s3 += a[5 + j] * gj;
            }
            *(float4*)&s_rc[r][c4] = make_float4(s0, s1, s2, s3);
        }
    }
    __syncthreads();

    // ---- Phase 3: col conv (float4 rows) + analytic dens -> scale ----
    {
        int ly  = t >> 4;
        int lx4 = (t & 15) << 2;
        if (tx0 + lx4 < w) {                 // only false on L3 (w=32)
            float4 acc = {0.f, 0.f, 0.f, 0.f};
#pragma unroll
            for (int j = 0; j < 13; j++) {
                float4 v = *(const float4*)&s_rc[ly + j][lx4];
                float gj = G1[j];
                acc.x += v.x * gj; acc.y += v.y * gj;
                acc.z += v.z * gj; acc.w += v.w * gj;
            }
            int gy = ty0 + ly;
            int ylo = min(RAD, gy), yhi = min(RAD, h - 1 - gy);
            float Sy = PRE[RAD + yhi + 1] - PRE[RAD - ylo];
            float4 sc;
#pragma unroll
            for (int d = 0; d < 4; d++) {
                int gx = tx0 + lx4 + d;
                int xlo = min(RAD, gx), xhi = min(RAD, w - 1 - gx);
                float Sx = PRE[RAD + xhi + 1] - PRE[RAD - xlo];
                float dens = WSUM * Sy * Sx;
                float s = (d == 0) ? acc.x : (d == 1) ? acc.y : (d == 2) ? acc.z : acc.w;
                float r = dens / (s + EPSV * dens);   // == 1/(s/dens + eps)
                if (d == 0) sc.x = r; else if (d == 1) sc.y = r;
                else if (d == 2) sc.z = r; else sc.w = r;
            }
            *(float4*)&s_scale[ly][lx4] = sc;
        }
    }
    __syncthreads();

    // ---- Phase 4: scale retained RGB, per-pixel float3 store (dense) ----
#pragma unroll
    for (int j = 0; j < 4; j++) {
        int P   = t + (j << 8);
        int row = P >> 6, col = P & 63;
        int gx  = tx0 + col;
        if (gx < w) {
            float sc = s_scale[row][col];   // stride-1 b32 read, conflict-free
            F3 v = pf[j];
            v.x *= sc; v.y *= sc; v.z *= sc;
            *(F3*)(ob + ((size_t)(ty0 + row) * w + gx) * 3) = v;
        }
    }
}

extern "C" void kernel_launch(void* const* d_in, const int* in_sizes, int n_in,
                              void* d_out, int out_size, void* d_ws, size_t ws_size,
                              hipStream_t stream) {
    const float* x = (const float*)d_in[0];
    float* out = (float*)d_out;
    mslln_kernel<<<NBLK, 256, 0, stream>>>(x, out);
}